// Round 19
// baseline (97.636 us; speedup 1.0000x reference)
//
#include <hip/hip_runtime.h>
#include <hip/hip_fp16.h>

// MessagePassing: 10 iterations of 3x3 per-pixel-weighted smoothing.
//   input [8,64,128,128] f32, weight [8,9,128,128] f32 -> out [8,64,128,128] f32
// R19 = R18 (best: 88.8us) + b-only load/store phase overlap:
//   chunk-0 load in prologue; inside the loop, chunk-(i+1)'s 4 volatile
//   staged loads issue BEFORE the store phase, commit to the dead LDS buffer
//   after it (volatile = program-order pinned; waitcnt lands at the commit
//   ds_writes, so L2 latency hides under the 512 global stores). 16 staged
//   regs live only through the low-pressure store phase. One barrier saved.
// a untouched (proven clean at ~50us; this loop spills if you breathe on it).
// Kill-check: if b's WRITE >> 40MB -> R7-style stage spill -> ship R18 final.

#define NB    8
#define CC    64
#define HH    128
#define WW    128
#define TAPS  9
#define PLANE (HH * WW)

#define CORE   16            // output tile rows per kernel
#define HALO5  5
#define RROWS  26            // CORE + 2*HALO5
#define RSTR4  129           // x-buffer row stride in cells (uint4)
#define NTH    832           // 26 rows * 32 strips, 13 waves
#define NSTEP  5
#define CGRP   16            // channels per block
#define CSUB   8             // channels per chunk (fp16 x8 in uint4 cell)
#define WROWS  24            // weight rows resident (region rows 1..24)
#define WCELLS (WROWS * TAPS * 32)   // half4 (uint2) cells = 6912 (55,296 B)

#define PERM4(J) ((((J) & 3) << 5) | ((J) >> 2))   // bijective on 0..127

typedef unsigned int u32x4 __attribute__((ext_vector_type(4)));

__device__ __forceinline__ float4 fma4(const float4 a, const float s, const float4 c) {
    return make_float4(fmaf(a.x, s, c.x), fmaf(a.y, s, c.y),
                       fmaf(a.z, s, c.z), fmaf(a.w, s, c.w));
}

__device__ __forceinline__ float4 cvt_lo(const uint4 v) {   // ch0-3
    const float2 a = __half22float2(*reinterpret_cast<const __half2*>(&v.x));
    const float2 b = __half22float2(*reinterpret_cast<const __half2*>(&v.y));
    return make_float4(a.x, a.y, b.x, b.y);
}
__device__ __forceinline__ float4 cvt_hi(const uint4 v) {   // ch4-7
    const float2 a = __half22float2(*reinterpret_cast<const __half2*>(&v.z));
    const float2 b = __half22float2(*reinterpret_cast<const __half2*>(&v.w));
    return make_float4(a.x, a.y, b.x, b.y);
}
__device__ __forceinline__ unsigned pack2(float a, float b) {
    __half2 h = __floats2half2_rn(a, b);
    return *reinterpret_cast<unsigned*>(&h);
}

// Normalize taps, store fp16: layout [n][9][128][32] uint2 (half4 cells).
__global__ __launch_bounds__(256) void mp_norm_kernel(const float* __restrict__ w,
                                                      uint2* __restrict__ nwh) {
    int tid = blockIdx.x * 256 + threadIdx.x;       // 32768 threads
    int wg = tid & 31;
    int h  = (tid >> 5) & 127;
    int n  = tid >> 12;
    int base = n * TAPS * PLANE + h * WW + wg * 4;
    float4 t[TAPS];
    float sx = 1e-5f, sy = 1e-5f, sz = 1e-5f, sw = 1e-5f;
#pragma unroll
    for (int k = 0; k < TAPS; ++k) {
        t[k] = *reinterpret_cast<const float4*>(w + base + k * PLANE);
        sx += t[k].x; sy += t[k].y; sz += t[k].z; sw += t[k].w;
    }
    float rx = 1.0f / sx, ry = 1.0f / sy, rz = 1.0f / sz, rw = 1.0f / sw;
#pragma unroll
    for (int k = 0; k < TAPS; ++k) {
        uint2 v;
        v.x = pack2(t[k].x * rx, t[k].y * ry);
        v.y = pack2(t[k].z * rz, t[k].w * rw);
        nwh[((n * TAPS + k) * HH + h) * 32 + wg] = v;
    }
}

// Shared pieces (macros so both kernels get byte-identical step loops without
// any shared template/function regalloc context).
#define FUSED_PROLOGUE                                                          \
    __shared__ uint4 bufA[RROWS * RSTR4];                                       \
    __shared__ uint4 bufB[RROWS * RSTR4];                                       \
    __shared__ uint2 wlds[WCELLS];                                              \
    const int bid = blockIdx.x;                                                 \
    const int n   = bid & 7;                                                    \
    const int ht  = (bid >> 3) & 7;                                             \
    const int cg  = bid >> 6;                                                   \
    const int tr0 = ht * CORE;                                                  \
    const int cb  = cg * CGRP;                                                  \
    const int t   = threadIdx.x;                                                \
    const int row = t >> 5;                                                     \
    const int s   = t & 31;                                                     \
    {                                                                           \
        const uint2* nwb = nwh + (size_t)n * TAPS * (PLANE / 4);                \
        for (int idx = t; idx < WCELLS; idx += NTH) {                           \
            const int wrow = idx / (TAPS * 32);                                 \
            const int rem  = idx - wrow * (TAPS * 32);                          \
            const int k    = rem >> 5;                                          \
            const int ss   = rem & 31;                                          \
            const int gr   = tr0 - (HALO5 - 1) + wrow;                          \
            uint2 v = make_uint2(0u, 0u);                                       \
            if (gr >= 0 && gr < HH)                                             \
                v = nwb[(k * HH + gr) * 32 + ss];                               \
            wlds[idx] = v;                                                      \
        }                                                                       \
    }                                                                           \
    const uint4 zc = make_uint4(0u, 0u, 0u, 0u);                                \
    const float4 z = make_float4(0.f, 0.f, 0.f, 0.f);

#define FUSED_STEPS                                                             \
        uint4* pin  = bufA;                                                     \
        uint4* pout = bufB;                                                     \
        for (int st = 0; st < NSTEP; ++st) {                                    \
            const int lo = st + 1;                                              \
            const int hi = 24 - st;                                             \
            if (row >= lo && row <= hi) {                                       \
                int wb = (row - 1) * (TAPS * 32) + s;                           \
                asm volatile("" : "+v"(wb));                                    \
                float4 aL0 = z, aL1 = z, aL2 = z, aL3 = z;                      \
                float4 aH0 = z, aH1 = z, aH2 = z, aH3 = z;                      \
                _Pragma("unroll")                                               \
                for (int di = 0; di < 3; ++di) {                                \
                    const uint4* rp = pin + (row - 1 + di) * RSTR4;             \
                    uint4 x[6];                                                 \
                    x[0] = (s > 0) ? rp[96 + s - 1] : zc;                       \
                    x[1] = rp[s];                                               \
                    x[2] = rp[32 + s];                                          \
                    x[3] = rp[64 + s];                                          \
                    x[4] = rp[96 + s];                                          \
                    x[5] = (s < 31) ? rp[s + 1] : zc;                           \
                    _Pragma("unroll")                                           \
                    for (int dj = 0; dj < 3; ++dj) {                            \
                        const int k = di * 3 + dj;                              \
                        const uint2 wv = wlds[wb + k * 32];                     \
                        const float2 w01 = __half22float2(*reinterpret_cast<const __half2*>(&wv.x)); \
                        const float2 w23 = __half22float2(*reinterpret_cast<const __half2*>(&wv.y)); \
                        aL0 = fma4(cvt_lo(x[0 + dj]), w01.x, aL0);              \
                        aH0 = fma4(cvt_hi(x[0 + dj]), w01.x, aH0);              \
                        aL1 = fma4(cvt_lo(x[1 + dj]), w01.y, aL1);              \
                        aH1 = fma4(cvt_hi(x[1 + dj]), w01.y, aH1);              \
                        aL2 = fma4(cvt_lo(x[2 + dj]), w23.x, aL2);              \
                        aH2 = fma4(cvt_hi(x[2 + dj]), w23.x, aH2);              \
                        aL3 = fma4(cvt_lo(x[3 + dj]), w23.y, aL3);              \
                        aH3 = fma4(cvt_hi(x[3 + dj]), w23.y, aH3);              \
                    }                                                           \
                }                                                               \
                uint4* op = pout + row * RSTR4;                                 \
                uint4 o0, o1, o2, o3;                                           \
                o0.x = pack2(aL0.x, aL0.y); o0.y = pack2(aL0.z, aL0.w);         \
                o0.z = pack2(aH0.x, aH0.y); o0.w = pack2(aH0.z, aH0.w);         \
                o1.x = pack2(aL1.x, aL1.y); o1.y = pack2(aL1.z, aL1.w);         \
                o1.z = pack2(aH1.x, aH1.y); o1.w = pack2(aH1.z, aH1.w);         \
                o2.x = pack2(aL2.x, aL2.y); o2.y = pack2(aL2.z, aL2.w);         \
                o2.z = pack2(aH2.x, aH2.y); o2.w = pack2(aH2.z, aH2.w);         \
                o3.x = pack2(aL3.x, aL3.y); o3.y = pack2(aL3.z, aL3.w);         \
                o3.z = pack2(aH3.x, aH3.y); o3.w = pack2(aH3.z, aH3.w);         \
                op[s]      = o0;                                                \
                op[32 + s] = o1;                                                \
                op[64 + s] = o2;                                                \
                op[96 + s] = o3;                                                \
            }                                                                   \
            __syncthreads();                                                    \
            uint4* tmp = pin; pin = pout; pout = tmp;                           \
        }

// ---- A: f32 source -> fp16-cell intermediate (UNCHANGED: clean, ~50us) ----
__global__ __launch_bounds__(NTH, 1) void mp_fused5_a(const float* __restrict__ src,
                                                      uint4* __restrict__ dst16,
                                                      const uint2* __restrict__ nwh) {
    FUSED_PROLOGUE
    for (int ch = 0; ch < CGRP; ch += CSUB) {            // 2 chunks
        const float* sp = src + ((size_t)n * CC + cb + ch) * PLANE;
        for (int idx = t; idx < RROWS * WW; idx += NTH) {
            const int r  = idx >> 7;
            const int J  = idx & 127;
            const int gr = tr0 - HALO5 + r;
            uint4 v = zc;
            if (gr >= 0 && gr < HH) {
                const int o = gr * WW + J;
                v.x = pack2(sp[o],             sp[PLANE + o]);
                v.y = pack2(sp[2 * PLANE + o], sp[3 * PLANE + o]);
                v.z = pack2(sp[4 * PLANE + o], sp[5 * PLANE + o]);
                v.w = pack2(sp[6 * PLANE + o], sp[7 * PLANE + o]);
            }
            bufA[r * RSTR4 + PERM4(J)] = v;
        }
        __syncthreads();
        FUSED_STEPS
        uint4* dp16 = dst16 + ((size_t)n * (CC / 8) + ((cb + ch) >> 3)) * PLANE;
        for (int idx = t; idx < CORE * WW; idx += NTH) {
            const int r = idx >> 7;
            const int J = idx & 127;
            dp16[(tr0 + r) * WW + J] = pin[(r + HALO5) * RSTR4 + PERM4(J)];
        }
        __syncthreads();
    }
}

// ---- B: fp16-cell intermediate -> f32 dest (volatile x4 loads + prefetch
//      of next chunk's region under the store phase) ----
__global__ __launch_bounds__(NTH, 1) void mp_fused5_b(const uint4* __restrict__ src16,
                                                      float* __restrict__ dst,
                                                      const uint2* __restrict__ nwh) {
    FUSED_PROLOGUE
    // prologue: chunk 0 region -> bufA (volatile x4 loads, proven clean R18)
    {
        const volatile u32x4* sp16v =
            (const volatile u32x4*)(src16 + ((size_t)n * (CC / 8) + (cb >> 3)) * PLANE);
        for (int idx = t; idx < RROWS * WW; idx += NTH) {
            const int r  = idx >> 7;
            const int J  = idx & 127;
            const int gr = tr0 - HALO5 + r;
            uint4 v = zc;
            if (gr >= 0 && gr < HH) {
                const u32x4 w = sp16v[gr * WW + J];
                v = make_uint4(w.x, w.y, w.z, w.w);
            }
            bufA[r * RSTR4 + PERM4(J)] = v;
        }
    }
    __syncthreads();
#pragma unroll 1
    for (int ch = 0; ch < CGRP; ch += CSUB) {            // 2 chunks, NOT unrolled
        FUSED_STEPS
        // After 5 steps: result in pin (=bufB), bufA dead (last read was st4,
        // covered by the final step barrier).

        // ---- stage next chunk's region loads (issued BEFORE the store; the
        //      waitcnt binds at the commit ds_writes below) ----
        const bool more = (ch + CSUB < CGRP);
        u32x4 sv0, sv1, sv2, sv3;
        bool k0 = false, k1 = false, k2 = false, k3 = false;
        if (more) {
            const volatile u32x4* sp16v =
                (const volatile u32x4*)(src16 +
                    ((size_t)n * (CC / 8) + ((cb + ch + CSUB) >> 3)) * PLANE);
            const int g0 = tr0 - HALO5 + ((t) >> 7);
            const int g1 = tr0 - HALO5 + ((t + NTH) >> 7);
            const int g2 = tr0 - HALO5 + ((t + 2 * NTH) >> 7);
            const int g3 = tr0 - HALO5 + ((t + 3 * NTH) >> 7);
            k0 = (g0 >= 0 && g0 < HH); k1 = (g1 >= 0 && g1 < HH);
            k2 = (g2 >= 0 && g2 < HH); k3 = (g3 >= 0 && g3 < HH);
            sv0 = sp16v[min(max(g0, 0), HH - 1) * WW + ((t) & 127)];
            sv1 = sp16v[min(max(g1, 0), HH - 1) * WW + ((t + NTH) & 127)];
            sv2 = sp16v[min(max(g2, 0), HH - 1) * WW + ((t + 2 * NTH) & 127)];
            sv3 = sp16v[min(max(g3, 0), HH - 1) * WW + ((t + 3 * NTH) & 127)];
        }

        // ---- store 16x128 core x 8 channels (overlaps staged-load latency) ----
        {
            float* dp = dst + ((size_t)n * CC + cb + ch) * PLANE;
            for (int idx = t; idx < CORE * WW; idx += NTH) {
                const int r = idx >> 7;
                const int J = idx & 127;
                const uint4 v = pin[(r + HALO5) * RSTR4 + PERM4(J)];
                const float4 lo = cvt_lo(v);
                const float4 hi = cvt_hi(v);
                const int o = (tr0 + r) * WW + J;
                dp[o]             = lo.x;
                dp[PLANE + o]     = lo.y;
                dp[2 * PLANE + o] = lo.z;
                dp[3 * PLANE + o] = lo.w;
                dp[4 * PLANE + o] = hi.x;
                dp[5 * PLANE + o] = hi.y;
                dp[6 * PLANE + o] = hi.z;
                dp[7 * PLANE + o] = hi.w;
            }
        }

        // ---- commit staged region into bufA (dead since the last step bar) ----
        if (more) {
            bufA[((t) >> 7) * RSTR4 + PERM4((t) & 127)] =
                k0 ? make_uint4(sv0.x, sv0.y, sv0.z, sv0.w) : zc;
            bufA[((t + NTH) >> 7) * RSTR4 + PERM4((t + NTH) & 127)] =
                k1 ? make_uint4(sv1.x, sv1.y, sv1.z, sv1.w) : zc;
            bufA[((t + 2 * NTH) >> 7) * RSTR4 + PERM4((t + 2 * NTH) & 127)] =
                k2 ? make_uint4(sv2.x, sv2.y, sv2.z, sv2.w) : zc;
            bufA[((t + 3 * NTH) >> 7) * RSTR4 + PERM4((t + 3 * NTH) & 127)] =
                k3 ? make_uint4(sv3.x, sv3.y, sv3.z, sv3.w) : zc;
        }
        __syncthreads();   // commits visible + bufB reads done before next steps
    }
}

extern "C" void kernel_launch(void* const* d_in, const int* in_sizes, int n_in,
                              void* d_out, int out_size, void* d_ws, size_t ws_size,
                              hipStream_t stream) {
    const float* input  = (const float*)d_in[0];
    const float* weight = (const float*)d_in[1];
    float* out = (float*)d_out;

    uint2* nwh = (uint2*)d_ws;                               // 2.36 MB fp16 weights
    uint4* B0  = (uint4*)((char*)d_ws + (size_t)NB * TAPS * PLANE * 2);  // 16.8 MB fp16 cells

    mp_norm_kernel<<<128, 256, 0, stream>>>(weight, nwh);
    mp_fused5_a<<<256, NTH, 0, stream>>>(input, B0, nwh);    // steps 1..5
    mp_fused5_b<<<256, NTH, 0, stream>>>(B0, out, nwh);      // steps 6..10
}

// Round 20
// 87.476 us; speedup vs baseline: 1.1161x; 1.1161x over previous
//
#include <hip/hip_runtime.h>
#include <hip/hip_fp16.h>

// MessagePassing: 10 iterations of 3x3 per-pixel-weighted smoothing.
//   input [8,64,128,128] f32, weight [8,9,128,128] f32 -> out [8,64,128,128] f32
// R20 = R18 (best: 88.8us; R19's store-overlap re-spilled and is reverted)
// with the step-loop inner product emitted as v_fma_mix_f32 inline asm:
// f16 x-operand promoted IN the FMA (op_sel picks half), f32 accumulate.
// Removes ~144 v_cvt_f32_f16 per thread-step (31% of step VALU) and the
// float temporaries (lower pressure). Bit-identical math (f16->f32 promote
// inside fma_mix is exact) -> absmax must stay exactly 0.00390625.
// Kill-checks: VGPR<=64, WRITE a=16.4MB b=32.8MB; else revert to R18 final.

#define NB    8
#define CC    64
#define HH    128
#define WW    128
#define TAPS  9
#define PLANE (HH * WW)

#define CORE   16            // output tile rows per kernel
#define HALO5  5
#define RROWS  26            // CORE + 2*HALO5
#define RSTR4  129           // x-buffer row stride in cells (uint4)
#define NTH    832           // 26 rows * 32 strips, 13 waves
#define NSTEP  5
#define CGRP   16            // channels per block
#define CSUB   8             // channels per chunk (fp16 x8 in uint4 cell)
#define WROWS  24            // weight rows resident (region rows 1..24)
#define WCELLS (WROWS * TAPS * 32)   // half4 (uint2) cells = 6912 (55,296 B)

#define PERM4(J) ((((J) & 3) << 5) | ((J) >> 2))   // bijective on 0..127

typedef unsigned int u32x4 __attribute__((ext_vector_type(4)));

// v_fma_mix_f32: acc(f32) += f16(lo/hi of xh) * wf(f32). Exact f16 promote.
#define MIXLO(acc, xh, wf)                                                      \
    asm("v_fma_mix_f32 %0, %1, %2, %0 op_sel:[0,0,0] op_sel_hi:[1,0,0]"         \
        : "+v"(acc) : "v"(xh), "v"(wf))
#define MIXHI(acc, xh, wf)                                                      \
    asm("v_fma_mix_f32 %0, %1, %2, %0 op_sel:[1,0,0] op_sel_hi:[1,0,0]"         \
        : "+v"(acc) : "v"(xh), "v"(wf))
// 8 channels of one cell against one scalar weight.
#define MIX8(aL, aH, cell, wf)                                                  \
    MIXLO(aL.x, cell.x, wf); MIXHI(aL.y, cell.x, wf);                           \
    MIXLO(aL.z, cell.y, wf); MIXHI(aL.w, cell.y, wf);                           \
    MIXLO(aH.x, cell.z, wf); MIXHI(aH.y, cell.z, wf);                           \
    MIXLO(aH.z, cell.w, wf); MIXHI(aH.w, cell.w, wf)

__device__ __forceinline__ float4 cvt_lo(const uint4 v) {   // ch0-3 (store phase)
    const float2 a = __half22float2(*reinterpret_cast<const __half2*>(&v.x));
    const float2 b = __half22float2(*reinterpret_cast<const __half2*>(&v.y));
    return make_float4(a.x, a.y, b.x, b.y);
}
__device__ __forceinline__ float4 cvt_hi(const uint4 v) {   // ch4-7 (store phase)
    const float2 a = __half22float2(*reinterpret_cast<const __half2*>(&v.z));
    const float2 b = __half22float2(*reinterpret_cast<const __half2*>(&v.w));
    return make_float4(a.x, a.y, b.x, b.y);
}
__device__ __forceinline__ unsigned pack2(float a, float b) {
    __half2 h = __floats2half2_rn(a, b);
    return *reinterpret_cast<unsigned*>(&h);
}
__device__ __forceinline__ float2 h22f2(unsigned u) {
    return __half22float2(*reinterpret_cast<const __half2*>(&u));
}

// Normalize taps, store fp16: layout [n][9][128][32] uint2 (half4 cells).
__global__ __launch_bounds__(256) void mp_norm_kernel(const float* __restrict__ w,
                                                      uint2* __restrict__ nwh) {
    int tid = blockIdx.x * 256 + threadIdx.x;       // 32768 threads
    int wg = tid & 31;
    int h  = (tid >> 5) & 127;
    int n  = tid >> 12;
    int base = n * TAPS * PLANE + h * WW + wg * 4;
    float4 t[TAPS];
    float sx = 1e-5f, sy = 1e-5f, sz = 1e-5f, sw = 1e-5f;
#pragma unroll
    for (int k = 0; k < TAPS; ++k) {
        t[k] = *reinterpret_cast<const float4*>(w + base + k * PLANE);
        sx += t[k].x; sy += t[k].y; sz += t[k].z; sw += t[k].w;
    }
    float rx = 1.0f / sx, ry = 1.0f / sy, rz = 1.0f / sz, rw = 1.0f / sw;
#pragma unroll
    for (int k = 0; k < TAPS; ++k) {
        uint2 v;
        v.x = pack2(t[k].x * rx, t[k].y * ry);
        v.y = pack2(t[k].z * rz, t[k].w * rw);
        nwh[((n * TAPS + k) * HH + h) * 32 + wg] = v;
    }
}

// Shared pieces (macros so both kernels get byte-identical step loops without
// any shared template/function regalloc context).
#define FUSED_PROLOGUE                                                          \
    __shared__ uint4 bufA[RROWS * RSTR4];                                       \
    __shared__ uint4 bufB[RROWS * RSTR4];                                       \
    __shared__ uint2 wlds[WCELLS];                                              \
    const int bid = blockIdx.x;                                                 \
    const int n   = bid & 7;                                                    \
    const int ht  = (bid >> 3) & 7;                                             \
    const int cg  = bid >> 6;                                                   \
    const int tr0 = ht * CORE;                                                  \
    const int cb  = cg * CGRP;                                                  \
    const int t   = threadIdx.x;                                                \
    const int row = t >> 5;                                                     \
    const int s   = t & 31;                                                     \
    {                                                                           \
        const uint2* nwb = nwh + (size_t)n * TAPS * (PLANE / 4);                \
        for (int idx = t; idx < WCELLS; idx += NTH) {                           \
            const int wrow = idx / (TAPS * 32);                                 \
            const int rem  = idx - wrow * (TAPS * 32);                          \
            const int k    = rem >> 5;                                          \
            const int ss   = rem & 31;                                          \
            const int gr   = tr0 - (HALO5 - 1) + wrow;                          \
            uint2 v = make_uint2(0u, 0u);                                       \
            if (gr >= 0 && gr < HH)                                             \
                v = nwb[(k * HH + gr) * 32 + ss];                               \
            wlds[idx] = v;                                                      \
        }                                                                       \
    }                                                                           \
    const uint4 zc = make_uint4(0u, 0u, 0u, 0u);                                \
    const float4 z = make_float4(0.f, 0.f, 0.f, 0.f);

#define FUSED_STEPS                                                             \
        uint4* pin  = bufA;                                                     \
        uint4* pout = bufB;                                                     \
        for (int st = 0; st < NSTEP; ++st) {                                    \
            const int lo = st + 1;                                              \
            const int hi = 24 - st;                                             \
            if (row >= lo && row <= hi) {                                       \
                int wb = (row - 1) * (TAPS * 32) + s;                           \
                asm volatile("" : "+v"(wb));                                    \
                float4 aL0 = z, aL1 = z, aL2 = z, aL3 = z;                      \
                float4 aH0 = z, aH1 = z, aH2 = z, aH3 = z;                      \
                _Pragma("unroll")                                               \
                for (int di = 0; di < 3; ++di) {                                \
                    const uint4* rp = pin + (row - 1 + di) * RSTR4;             \
                    uint4 x[6];                                                 \
                    x[0] = (s > 0) ? rp[96 + s - 1] : zc;                       \
                    x[1] = rp[s];                                               \
                    x[2] = rp[32 + s];                                          \
                    x[3] = rp[64 + s];                                          \
                    x[4] = rp[96 + s];                                          \
                    x[5] = (s < 31) ? rp[s + 1] : zc;                           \
                    _Pragma("unroll")                                           \
                    for (int dj = 0; dj < 3; ++dj) {                            \
                        const int k = di * 3 + dj;                              \
                        const uint2 wv = wlds[wb + k * 32];                     \
                        const float2 w01 = h22f2(wv.x);                         \
                        const float2 w23 = h22f2(wv.y);                         \
                        MIX8(aL0, aH0, x[0 + dj], w01.x);                       \
                        MIX8(aL1, aH1, x[1 + dj], w01.y);                       \
                        MIX8(aL2, aH2, x[2 + dj], w23.x);                       \
                        MIX8(aL3, aH3, x[3 + dj], w23.y);                       \
                    }                                                           \
                }                                                               \
                uint4* op = pout + row * RSTR4;                                 \
                uint4 o0, o1, o2, o3;                                           \
                o0.x = pack2(aL0.x, aL0.y); o0.y = pack2(aL0.z, aL0.w);         \
                o0.z = pack2(aH0.x, aH0.y); o0.w = pack2(aH0.z, aH0.w);         \
                o1.x = pack2(aL1.x, aL1.y); o1.y = pack2(aL1.z, aL1.w);         \
                o1.z = pack2(aH1.x, aH1.y); o1.w = pack2(aH1.z, aH1.w);         \
                o2.x = pack2(aL2.x, aL2.y); o2.y = pack2(aL2.z, aL2.w);         \
                o2.z = pack2(aH2.x, aH2.y); o2.w = pack2(aH2.z, aH2.w);         \
                o3.x = pack2(aL3.x, aL3.y); o3.y = pack2(aL3.z, aL3.w);         \
                o3.z = pack2(aH3.x, aH3.y); o3.w = pack2(aH3.z, aH3.w);         \
                op[s]      = o0;                                                \
                op[32 + s] = o1;                                                \
                op[64 + s] = o2;                                                \
                op[96 + s] = o3;                                                \
            }                                                                   \
            __syncthreads();                                                    \
            uint4* tmp = pin; pin = pout; pout = tmp;                           \
        }

// ---- A: f32 source -> fp16-cell intermediate ----
__global__ __launch_bounds__(NTH, 1) void mp_fused5_a(const float* __restrict__ src,
                                                      uint4* __restrict__ dst16,
                                                      const uint2* __restrict__ nwh) {
    FUSED_PROLOGUE
    for (int ch = 0; ch < CGRP; ch += CSUB) {            // 2 chunks
        const float* sp = src + ((size_t)n * CC + cb + ch) * PLANE;
        for (int idx = t; idx < RROWS * WW; idx += NTH) {
            const int r  = idx >> 7;
            const int J  = idx & 127;
            const int gr = tr0 - HALO5 + r;
            uint4 v = zc;
            if (gr >= 0 && gr < HH) {
                const int o = gr * WW + J;
                v.x = pack2(sp[o],             sp[PLANE + o]);
                v.y = pack2(sp[2 * PLANE + o], sp[3 * PLANE + o]);
                v.z = pack2(sp[4 * PLANE + o], sp[5 * PLANE + o]);
                v.w = pack2(sp[6 * PLANE + o], sp[7 * PLANE + o]);
            }
            bufA[r * RSTR4 + PERM4(J)] = v;
        }
        __syncthreads();
        FUSED_STEPS
        uint4* dp16 = dst16 + ((size_t)n * (CC / 8) + ((cb + ch) >> 3)) * PLANE;
        for (int idx = t; idx < CORE * WW; idx += NTH) {
            const int r = idx >> 7;
            const int J = idx & 127;
            dp16[(tr0 + r) * WW + J] = pin[(r + HALO5) * RSTR4 + PERM4(J)];
        }
        __syncthreads();
    }
}

// ---- B: fp16-cell intermediate -> f32 dest (volatile x4 loads, R18-proven) ----
__global__ __launch_bounds__(NTH, 1) void mp_fused5_b(const uint4* __restrict__ src16,
                                                      float* __restrict__ dst,
                                                      const uint2* __restrict__ nwh) {
    FUSED_PROLOGUE
#pragma unroll 1
    for (int ch = 0; ch < CGRP; ch += CSUB) {            // 2 chunks, NOT unrolled
        const volatile u32x4* sp16v =
            (const volatile u32x4*)(src16 + ((size_t)n * (CC / 8) + ((cb + ch) >> 3)) * PLANE);
        for (int idx = t; idx < RROWS * WW; idx += NTH) {
            const int r  = idx >> 7;
            const int J  = idx & 127;
            const int gr = tr0 - HALO5 + r;
            uint4 v = zc;
            if (gr >= 0 && gr < HH) {
                const u32x4 w = sp16v[gr * WW + J];
                v = make_uint4(w.x, w.y, w.z, w.w);
            }
            bufA[r * RSTR4 + PERM4(J)] = v;
        }
        __syncthreads();
        FUSED_STEPS
        float* dp = dst + ((size_t)n * CC + cb + ch) * PLANE;
        for (int idx = t; idx < CORE * WW; idx += NTH) {
            const int r = idx >> 7;
            const int J = idx & 127;
            const uint4 v = pin[(r + HALO5) * RSTR4 + PERM4(J)];
            const float4 lo = cvt_lo(v);
            const float4 hi = cvt_hi(v);
            const int o = (tr0 + r) * WW + J;
            dp[o]             = lo.x;
            dp[PLANE + o]     = lo.y;
            dp[2 * PLANE + o] = lo.z;
            dp[3 * PLANE + o] = lo.w;
            dp[4 * PLANE + o] = hi.x;
            dp[5 * PLANE + o] = hi.y;
            dp[6 * PLANE + o] = hi.z;
            dp[7 * PLANE + o] = hi.w;
        }
        __syncthreads();
    }
}

extern "C" void kernel_launch(void* const* d_in, const int* in_sizes, int n_in,
                              void* d_out, int out_size, void* d_ws, size_t ws_size,
                              hipStream_t stream) {
    const float* input  = (const float*)d_in[0];
    const float* weight = (const float*)d_in[1];
    float* out = (float*)d_out;

    uint2* nwh = (uint2*)d_ws;                               // 2.36 MB fp16 weights
    uint4* B0  = (uint4*)((char*)d_ws + (size_t)NB * TAPS * PLANE * 2);  // 16.8 MB fp16 cells

    mp_norm_kernel<<<128, 256, 0, stream>>>(weight, nwh);
    mp_fused5_a<<<256, NTH, 0, stream>>>(input, B0, nwh);    // steps 1..5
    mp_fused5_b<<<256, NTH, 0, stream>>>(B0, out, nwh);      // steps 6..10
}

// Round 21
// 87.334 us; speedup vs baseline: 1.1180x; 1.0016x over previous
//
#include <hip/hip_runtime.h>
#include <hip/hip_fp16.h>

// MessagePassing: 10 iterations of 3x3 per-pixel-weighted smoothing.
//   input [8,64,128,128] f32, weight [8,9,128,128] f32 -> out [8,64,128,128] f32
// R21 = R20 (best: 87.5us) + carried middle row:
// at step st+1, a thread's di=1 cells x[1..4] are exactly the uint4 outputs
// o0..o3 it wrote at step st (band shrinkage => always valid when needed).
// Carry them in registers across the barrier: 18 -> 14 ds_read_b128 per
// thread-step (-22% x-read traffic; LDS is the measured dominant pipe).
// +16 loop-carried regs (~68 peak, <=128 cap at 13 waves). Loop-carried
// values are the one class the allocator hasn't spilled all session.
// Kill-check: WRITE balloon or dur regression -> ship R20 as final.

#define NB    8
#define CC    64
#define HH    128
#define WW    128
#define TAPS  9
#define PLANE (HH * WW)

#define CORE   16            // output tile rows per kernel
#define HALO5  5
#define RROWS  26            // CORE + 2*HALO5
#define RSTR4  129           // x-buffer row stride in cells (uint4)
#define NTH    832           // 26 rows * 32 strips, 13 waves
#define NSTEP  5
#define CGRP   16            // channels per block
#define CSUB   8             // channels per chunk (fp16 x8 in uint4 cell)
#define WROWS  24            // weight rows resident (region rows 1..24)
#define WCELLS (WROWS * TAPS * 32)   // half4 (uint2) cells = 6912 (55,296 B)

#define PERM4(J) ((((J) & 3) << 5) | ((J) >> 2))   // bijective on 0..127

typedef unsigned int u32x4 __attribute__((ext_vector_type(4)));

// v_fma_mix_f32: acc(f32) += f16(lo/hi of xh) * wf(f32). Exact f16 promote.
#define MIXLO(acc, xh, wf)                                                      \
    asm("v_fma_mix_f32 %0, %1, %2, %0 op_sel:[0,0,0] op_sel_hi:[1,0,0]"         \
        : "+v"(acc) : "v"(xh), "v"(wf))
#define MIXHI(acc, xh, wf)                                                      \
    asm("v_fma_mix_f32 %0, %1, %2, %0 op_sel:[1,0,0] op_sel_hi:[1,0,0]"         \
        : "+v"(acc) : "v"(xh), "v"(wf))
// 8 channels of one cell against one scalar weight.
#define MIX8(aL, aH, cell, wf)                                                  \
    MIXLO(aL.x, cell.x, wf); MIXHI(aL.y, cell.x, wf);                           \
    MIXLO(aL.z, cell.y, wf); MIXHI(aL.w, cell.y, wf);                           \
    MIXLO(aH.x, cell.z, wf); MIXHI(aH.y, cell.z, wf);                           \
    MIXLO(aH.z, cell.w, wf); MIXHI(aH.w, cell.w, wf)

__device__ __forceinline__ float4 cvt_lo(const uint4 v) {   // ch0-3 (store phase)
    const float2 a = __half22float2(*reinterpret_cast<const __half2*>(&v.x));
    const float2 b = __half22float2(*reinterpret_cast<const __half2*>(&v.y));
    return make_float4(a.x, a.y, b.x, b.y);
}
__device__ __forceinline__ float4 cvt_hi(const uint4 v) {   // ch4-7 (store phase)
    const float2 a = __half22float2(*reinterpret_cast<const __half2*>(&v.z));
    const float2 b = __half22float2(*reinterpret_cast<const __half2*>(&v.w));
    return make_float4(a.x, a.y, b.x, b.y);
}
__device__ __forceinline__ unsigned pack2(float a, float b) {
    __half2 h = __floats2half2_rn(a, b);
    return *reinterpret_cast<unsigned*>(&h);
}
__device__ __forceinline__ float2 h22f2(unsigned u) {
    return __half22float2(*reinterpret_cast<const __half2*>(&u));
}

// Normalize taps, store fp16: layout [n][9][128][32] uint2 (half4 cells).
__global__ __launch_bounds__(256) void mp_norm_kernel(const float* __restrict__ w,
                                                      uint2* __restrict__ nwh) {
    int tid = blockIdx.x * 256 + threadIdx.x;       // 32768 threads
    int wg = tid & 31;
    int h  = (tid >> 5) & 127;
    int n  = tid >> 12;
    int base = n * TAPS * PLANE + h * WW + wg * 4;
    float4 t[TAPS];
    float sx = 1e-5f, sy = 1e-5f, sz = 1e-5f, sw = 1e-5f;
#pragma unroll
    for (int k = 0; k < TAPS; ++k) {
        t[k] = *reinterpret_cast<const float4*>(w + base + k * PLANE);
        sx += t[k].x; sy += t[k].y; sz += t[k].z; sw += t[k].w;
    }
    float rx = 1.0f / sx, ry = 1.0f / sy, rz = 1.0f / sz, rw = 1.0f / sw;
#pragma unroll
    for (int k = 0; k < TAPS; ++k) {
        uint2 v;
        v.x = pack2(t[k].x * rx, t[k].y * ry);
        v.y = pack2(t[k].z * rz, t[k].w * rw);
        nwh[((n * TAPS + k) * HH + h) * 32 + wg] = v;
    }
}

// Shared pieces (macros so both kernels get byte-identical step loops without
// any shared template/function regalloc context).
#define FUSED_PROLOGUE                                                          \
    __shared__ uint4 bufA[RROWS * RSTR4];                                       \
    __shared__ uint4 bufB[RROWS * RSTR4];                                       \
    __shared__ uint2 wlds[WCELLS];                                              \
    const int bid = blockIdx.x;                                                 \
    const int n   = bid & 7;                                                    \
    const int ht  = (bid >> 3) & 7;                                             \
    const int cg  = bid >> 6;                                                   \
    const int tr0 = ht * CORE;                                                  \
    const int cb  = cg * CGRP;                                                  \
    const int t   = threadIdx.x;                                                \
    const int row = t >> 5;                                                     \
    const int s   = t & 31;                                                     \
    {                                                                           \
        const uint2* nwb = nwh + (size_t)n * TAPS * (PLANE / 4);                \
        for (int idx = t; idx < WCELLS; idx += NTH) {                           \
            const int wrow = idx / (TAPS * 32);                                 \
            const int rem  = idx - wrow * (TAPS * 32);                          \
            const int k    = rem >> 5;                                          \
            const int ss   = rem & 31;                                          \
            const int gr   = tr0 - (HALO5 - 1) + wrow;                          \
            uint2 v = make_uint2(0u, 0u);                                       \
            if (gr >= 0 && gr < HH)                                             \
                v = nwb[(k * HH + gr) * 32 + ss];                               \
            wlds[idx] = v;                                                      \
        }                                                                       \
    }                                                                           \
    const uint4 zc = make_uint4(0u, 0u, 0u, 0u);                                \
    const float4 z = make_float4(0.f, 0.f, 0.f, 0.f);

#define FUSED_STEPS                                                             \
        uint4* pin  = bufA;                                                     \
        uint4* pout = bufB;                                                     \
        uint4 m1 = zc, m2 = zc, m3 = zc, m4 = zc; /* carried middle-row cells */\
        _Pragma("unroll")                                                       \
        for (int st = 0; st < NSTEP; ++st) {                                    \
            const int lo = st + 1;                                              \
            const int hi = 24 - st;                                             \
            if (row >= lo && row <= hi) {                                       \
                int wb = (row - 1) * (TAPS * 32) + s;                           \
                asm volatile("" : "+v"(wb));                                    \
                float4 aL0 = z, aL1 = z, aL2 = z, aL3 = z;                      \
                float4 aH0 = z, aH1 = z, aH2 = z, aH3 = z;                      \
                _Pragma("unroll")                                               \
                for (int di = 0; di < 3; ++di) {                                \
                    const uint4* rp = pin + (row - 1 + di) * RSTR4;             \
                    uint4 x[6];                                                 \
                    x[0] = (s > 0) ? rp[96 + s - 1] : zc;                       \
                    if (di == 1 && st > 0) {                                    \
                        x[1] = m1; x[2] = m2; x[3] = m3; x[4] = m4;             \
                    } else {                                                    \
                        x[1] = rp[s];                                           \
                        x[2] = rp[32 + s];                                      \
                        x[3] = rp[64 + s];                                      \
                        x[4] = rp[96 + s];                                      \
                    }                                                           \
                    x[5] = (s < 31) ? rp[s + 1] : zc;                           \
                    _Pragma("unroll")                                           \
                    for (int dj = 0; dj < 3; ++dj) {                            \
                        const int k = di * 3 + dj;                              \
                        const uint2 wv = wlds[wb + k * 32];                     \
                        const float2 w01 = h22f2(wv.x);                         \
                        const float2 w23 = h22f2(wv.y);                         \
                        MIX8(aL0, aH0, x[0 + dj], w01.x);                       \
                        MIX8(aL1, aH1, x[1 + dj], w01.y);                       \
                        MIX8(aL2, aH2, x[2 + dj], w23.x);                       \
                        MIX8(aL3, aH3, x[3 + dj], w23.y);                       \
                    }                                                           \
                }                                                               \
                uint4* op = pout + row * RSTR4;                                 \
                uint4 o0, o1, o2, o3;                                           \
                o0.x = pack2(aL0.x, aL0.y); o0.y = pack2(aL0.z, aL0.w);         \
                o0.z = pack2(aH0.x, aH0.y); o0.w = pack2(aH0.z, aH0.w);         \
                o1.x = pack2(aL1.x, aL1.y); o1.y = pack2(aL1.z, aL1.w);         \
                o1.z = pack2(aH1.x, aH1.y); o1.w = pack2(aH1.z, aH1.w);         \
                o2.x = pack2(aL2.x, aL2.y); o2.y = pack2(aL2.z, aL2.w);         \
                o2.z = pack2(aH2.x, aH2.y); o2.w = pack2(aH2.z, aH2.w);         \
                o3.x = pack2(aL3.x, aL3.y); o3.y = pack2(aL3.z, aL3.w);         \
                o3.z = pack2(aH3.x, aH3.y); o3.w = pack2(aH3.z, aH3.w);         \
                op[s]      = o0;                                                \
                op[32 + s] = o1;                                                \
                op[64 + s] = o2;                                                \
                op[96 + s] = o3;                                                \
                m1 = o0; m2 = o1; m3 = o2; m4 = o3;                             \
            }                                                                   \
            __syncthreads();                                                    \
            uint4* tmp = pin; pin = pout; pout = tmp;                           \
        }

// ---- A: f32 source -> fp16-cell intermediate ----
__global__ __launch_bounds__(NTH, 1) void mp_fused5_a(const float* __restrict__ src,
                                                      uint4* __restrict__ dst16,
                                                      const uint2* __restrict__ nwh) {
    FUSED_PROLOGUE
    for (int ch = 0; ch < CGRP; ch += CSUB) {            // 2 chunks
        const float* sp = src + ((size_t)n * CC + cb + ch) * PLANE;
        for (int idx = t; idx < RROWS * WW; idx += NTH) {
            const int r  = idx >> 7;
            const int J  = idx & 127;
            const int gr = tr0 - HALO5 + r;
            uint4 v = zc;
            if (gr >= 0 && gr < HH) {
                const int o = gr * WW + J;
                v.x = pack2(sp[o],             sp[PLANE + o]);
                v.y = pack2(sp[2 * PLANE + o], sp[3 * PLANE + o]);
                v.z = pack2(sp[4 * PLANE + o], sp[5 * PLANE + o]);
                v.w = pack2(sp[6 * PLANE + o], sp[7 * PLANE + o]);
            }
            bufA[r * RSTR4 + PERM4(J)] = v;
        }
        __syncthreads();
        FUSED_STEPS
        uint4* dp16 = dst16 + ((size_t)n * (CC / 8) + ((cb + ch) >> 3)) * PLANE;
        for (int idx = t; idx < CORE * WW; idx += NTH) {
            const int r = idx >> 7;
            const int J = idx & 127;
            dp16[(tr0 + r) * WW + J] = pin[(r + HALO5) * RSTR4 + PERM4(J)];
        }
        __syncthreads();
    }
}

// ---- B: fp16-cell intermediate -> f32 dest (volatile x4 loads, R18-proven) ----
__global__ __launch_bounds__(NTH, 1) void mp_fused5_b(const uint4* __restrict__ src16,
                                                      float* __restrict__ dst,
                                                      const uint2* __restrict__ nwh) {
    FUSED_PROLOGUE
#pragma unroll 1
    for (int ch = 0; ch < CGRP; ch += CSUB) {            // 2 chunks, NOT unrolled
        const volatile u32x4* sp16v =
            (const volatile u32x4*)(src16 + ((size_t)n * (CC / 8) + ((cb + ch) >> 3)) * PLANE);
        for (int idx = t; idx < RROWS * WW; idx += NTH) {
            const int r  = idx >> 7;
            const int J  = idx & 127;
            const int gr = tr0 - HALO5 + r;
            uint4 v = zc;
            if (gr >= 0 && gr < HH) {
                const u32x4 w = sp16v[gr * WW + J];
                v = make_uint4(w.x, w.y, w.z, w.w);
            }
            bufA[r * RSTR4 + PERM4(J)] = v;
        }
        __syncthreads();
        FUSED_STEPS
        float* dp = dst + ((size_t)n * CC + cb + ch) * PLANE;
        for (int idx = t; idx < CORE * WW; idx += NTH) {
            const int r = idx >> 7;
            const int J = idx & 127;
            const uint4 v = pin[(r + HALO5) * RSTR4 + PERM4(J)];
            const float4 lo = cvt_lo(v);
            const float4 hi = cvt_hi(v);
            const int o = (tr0 + r) * WW + J;
            dp[o]             = lo.x;
            dp[PLANE + o]     = lo.y;
            dp[2 * PLANE + o] = lo.z;
            dp[3 * PLANE + o] = lo.w;
            dp[4 * PLANE + o] = hi.x;
            dp[5 * PLANE + o] = hi.y;
            dp[6 * PLANE + o] = hi.z;
            dp[7 * PLANE + o] = hi.w;
        }
        __syncthreads();
    }
}

extern "C" void kernel_launch(void* const* d_in, const int* in_sizes, int n_in,
                              void* d_out, int out_size, void* d_ws, size_t ws_size,
                              hipStream_t stream) {
    const float* input  = (const float*)d_in[0];
    const float* weight = (const float*)d_in[1];
    float* out = (float*)d_out;

    uint2* nwh = (uint2*)d_ws;                               // 2.36 MB fp16 weights
    uint4* B0  = (uint4*)((char*)d_ws + (size_t)NB * TAPS * PLANE * 2);  // 16.8 MB fp16 cells

    mp_norm_kernel<<<128, 256, 0, stream>>>(weight, nwh);
    mp_fused5_a<<<256, NTH, 0, stream>>>(input, B0, nwh);    // steps 1..5
    mp_fused5_b<<<256, NTH, 0, stream>>>(B0, out, nwh);      // steps 6..10
}